// Round 1
// baseline (7614.601 us; speedup 1.0000x reference)
//
#include <hip/hip_runtime.h>

// ConvexPolytopeManifold: dual-PGD QP projection.
// B=4096, n=512, m=1024. fp32 throughout (round 1: correctness-first).
//
// reference:
//   Q = A @ A^T                          [m,m]  (symmetric)
//   y = x + u
//   c = y @ A^T - b                      [B,m]
//   lam=0; 50x: lam = relu(lam - 0.01*(lam@Q - c))
//   z = y - lam @ A                      [B,n]
//   Ax = z @ A^T; active = (Ax >= b - 1e-5)
//   masked = (u @ A^T) * active
//   lam=0; 10x: lam = relu(lam - 0.01*(lam@Q - masked)) * active
//   out = u - lam @ A

#define PROJ_ITERS 50
#define PROJU_ITERS 10
#define TOLV 1e-5f
#define STEPV 0.01f

constexpr int BM = 64, BN = 64, BK = 16;

__global__ void add_kernel(const float* __restrict__ a, const float* __restrict__ b,
                           float* __restrict__ o, int n) {
    int i = blockIdx.x * blockDim.x + threadIdx.x;
    int idx = i * 4;
    if (idx < n) {
        float4 av = *(const float4*)(a + idx);
        float4 bv = *(const float4*)(b + idx);
        float4 ov = make_float4(av.x + bv.x, av.y + bv.y, av.z + bv.z, av.w + bv.w);
        *(float4*)(o + idx) = ov;
    }
}

// C[i,j] = sum_k X[i,k] * W[j,k]   (WT=1: W is [N,K] row-major)
//        = sum_k X[i,k] * W[k,j]   (WT=0: W is [K,N] row-major)
// EPI: 0 store; 1 acc-bvec[col]; 2 relu(e0-step*(acc-e1));
//      3 relu(e0-step*(acc-e1))*e2; 4 e0-acc; 5 mask: act=(e0>=bvec[col]-TOL),
//      out=acc*act, e2=act
template<int EPI, int WT>
__global__ __launch_bounds__(256)
void gemm_k(const float* __restrict__ X, const float* __restrict__ W,
            float* __restrict__ out,
            const float* __restrict__ e0, const float* __restrict__ e1,
            float* __restrict__ e2, const float* __restrict__ bvec,
            int M, int N, int K) {
    __shared__ float Xs[BK][BM + 4];
    __shared__ float Ws[BK][BN + 4];

    const int tid = threadIdx.x;
    const int bm = blockIdx.x * BM;
    const int bn = blockIdx.y * BN;

    const int lr = tid >> 2;          // 0..63: tile row (M or N dim)
    const int lk = (tid & 3) << 2;    // 0,4,8,12: k chunk
    const int wkr = tid >> 4;         // 0..15: k row (WT=0)
    const int wnc = (tid & 15) << 2;  // 0..60: n col (WT=0)

    const int tm = (tid & 15) << 2;   // micro-tile row base
    const int tn = (tid >> 4) << 2;   // micro-tile col base

    float acc[4][4] = {};

    for (int k0 = 0; k0 < K; k0 += BK) {
        float4 xv = *(const float4*)(X + (size_t)(bm + lr) * K + (k0 + lk));
        Xs[lk + 0][lr] = xv.x; Xs[lk + 1][lr] = xv.y;
        Xs[lk + 2][lr] = xv.z; Xs[lk + 3][lr] = xv.w;
        if (WT) {
            float4 wv = *(const float4*)(W + (size_t)(bn + lr) * K + (k0 + lk));
            Ws[lk + 0][lr] = wv.x; Ws[lk + 1][lr] = wv.y;
            Ws[lk + 2][lr] = wv.z; Ws[lk + 3][lr] = wv.w;
        } else {
            float4 wv = *(const float4*)(W + (size_t)(k0 + wkr) * N + (bn + wnc));
            *(float4*)&Ws[wkr][wnc] = wv;
        }
        __syncthreads();
#pragma unroll
        for (int k = 0; k < BK; ++k) {
            float4 a4 = *(const float4*)&Xs[k][tm];
            float4 b4 = *(const float4*)&Ws[k][tn];
            acc[0][0] = fmaf(a4.x, b4.x, acc[0][0]);
            acc[0][1] = fmaf(a4.x, b4.y, acc[0][1]);
            acc[0][2] = fmaf(a4.x, b4.z, acc[0][2]);
            acc[0][3] = fmaf(a4.x, b4.w, acc[0][3]);
            acc[1][0] = fmaf(a4.y, b4.x, acc[1][0]);
            acc[1][1] = fmaf(a4.y, b4.y, acc[1][1]);
            acc[1][2] = fmaf(a4.y, b4.z, acc[1][2]);
            acc[1][3] = fmaf(a4.y, b4.w, acc[1][3]);
            acc[2][0] = fmaf(a4.z, b4.x, acc[2][0]);
            acc[2][1] = fmaf(a4.z, b4.y, acc[2][1]);
            acc[2][2] = fmaf(a4.z, b4.z, acc[2][2]);
            acc[2][3] = fmaf(a4.z, b4.w, acc[2][3]);
            acc[3][0] = fmaf(a4.w, b4.x, acc[3][0]);
            acc[3][1] = fmaf(a4.w, b4.y, acc[3][1]);
            acc[3][2] = fmaf(a4.w, b4.z, acc[3][2]);
            acc[3][3] = fmaf(a4.w, b4.w, acc[3][3]);
        }
        __syncthreads();
    }

#pragma unroll
    for (int ii = 0; ii < 4; ++ii) {
        int row = bm + tm + ii;
#pragma unroll
        for (int jj = 0; jj < 4; ++jj) {
            int col = bn + tn + jj;
            size_t idx = (size_t)row * N + col;
            float v = acc[ii][jj];
            if (EPI == 0) {
                out[idx] = v;
            } else if (EPI == 1) {
                out[idx] = v - bvec[col];
            } else if (EPI == 2) {
                out[idx] = fmaxf(fmaf(-STEPV, v - e1[idx], e0[idx]), 0.0f);
            } else if (EPI == 3) {
                out[idx] = fmaxf(fmaf(-STEPV, v - e1[idx], e0[idx]), 0.0f) * e2[idx];
            } else if (EPI == 4) {
                out[idx] = e0[idx] - v;
            } else if (EPI == 5) {
                float act = (e0[idx] >= bvec[col] - TOLV) ? 1.0f : 0.0f;
                out[idx] = v * act;
                e2[idx] = act;
            }
        }
    }
}

extern "C" void kernel_launch(void* const* d_in, const int* in_sizes, int n_in,
                              void* d_out, int out_size, void* d_ws, size_t ws_size,
                              hipStream_t stream) {
    const float* x = (const float*)d_in[0];  // [B,n]
    const float* u = (const float*)d_in[1];  // [B,n]
    const float* A = (const float*)d_in[2];  // [m,n]
    const float* b = (const float*)d_in[3];  // [m]
    float* out = (float*)d_out;              // [B,n]

    const int B = 4096, n = 512, m = 1024;

    float* ws = (float*)d_ws;
    float* y    = ws;                       // [B,n]  y = x+u, later z
    float* cbuf = y    + (size_t)B * n;     // [B,m]  c, later masked
    float* lamA = cbuf + (size_t)B * m;     // [B,m]
    float* lamB = lamA + (size_t)B * m;     // [B,m]
    float* Ax   = lamB + (size_t)B * m;     // [B,m]  Ax, later active
    float* Q    = Ax   + (size_t)B * m;     // [m,m]

    dim3 blk(256);

    // y = x + u
    add_kernel<<<(B * n / 4 + 255) / 256, 256, 0, stream>>>(x, u, y, B * n);

    // Q = A @ A^T
    gemm_k<0, 1><<<dim3(m / BM, m / BN), blk, 0, stream>>>(
        A, A, Q, nullptr, nullptr, nullptr, nullptr, m, m, n);

    // c = y @ A^T - b
    gemm_k<1, 1><<<dim3(B / BM, m / BN), blk, 0, stream>>>(
        y, A, cbuf, nullptr, nullptr, nullptr, b, B, m, n);

    // phase 1: lam=0; 50x lam = relu(lam - step*(lam@Q - c)); Q symmetric -> WT=1 with W=Q
    hipMemsetAsync(lamA, 0, (size_t)B * m * sizeof(float), stream);
    float* lin = lamA;
    float* lout = lamB;
    for (int it = 0; it < PROJ_ITERS; ++it) {
        gemm_k<2, 1><<<dim3(B / BM, m / BN), blk, 0, stream>>>(
            lin, Q, lout, lin, cbuf, nullptr, nullptr, B, m, m);
        float* t = lin; lin = lout; lout = t;
    }

    // z = y - lam @ A   (in-place into y; A is [K=m, N=n] row-major -> WT=0)
    gemm_k<4, 0><<<dim3(B / BM, n / BN), blk, 0, stream>>>(
        lin, A, y, y, nullptr, nullptr, nullptr, B, n, m);

    // Ax = z @ A^T
    gemm_k<0, 1><<<dim3(B / BM, m / BN), blk, 0, stream>>>(
        y, A, Ax, nullptr, nullptr, nullptr, nullptr, B, m, n);

    // masked = (u @ A^T) * active -> cbuf; active -> Ax (overwrite, same idx)
    gemm_k<5, 1><<<dim3(B / BM, m / BN), blk, 0, stream>>>(
        u, A, cbuf, Ax, nullptr, Ax, b, B, m, n);

    // phase 2: lam=0; 10x lam = relu(lam - step*(lam@Q - masked)) * active
    hipMemsetAsync(lamA, 0, (size_t)B * m * sizeof(float), stream);
    lin = lamA; lout = lamB;
    for (int it = 0; it < PROJU_ITERS; ++it) {
        gemm_k<3, 1><<<dim3(B / BM, m / BN), blk, 0, stream>>>(
            lin, Q, lout, lin, cbuf, Ax, nullptr, B, m, m);
        float* t = lin; lin = lout; lout = t;
    }

    // out = u - lam @ A
    gemm_k<4, 0><<<dim3(B / BM, n / BN), blk, 0, stream>>>(
        lin, A, out, u, nullptr, nullptr, nullptr, B, n, m);
}

// Round 2
// 2007.274 us; speedup vs baseline: 3.7935x; 3.7935x over previous
//
#include <hip/hip_runtime.h>

// ConvexPolytopeManifold: dual-PGD QP projection. B=4096, n=512, m=1024.
// Round 2: 60 iteration GEMMs (lam@Q) -> bf16 MFMA (16x16x32) with fp32 lam
// master copy; everything else stays fp32 vector GEMM.

#define PROJ_ITERS 50
#define PROJU_ITERS 10
#define TOLV 1e-5f
#define STEPV 0.01f

typedef __attribute__((ext_vector_type(8))) short short8;
typedef __attribute__((ext_vector_type(4))) float floatx4;

__device__ inline unsigned short f2bf(float f) {
    union { float f; unsigned int u; } c; c.f = f;
    unsigned int u = c.u;
    unsigned int r = (u + 0x7FFFu + ((u >> 16) & 1u)) >> 16;   // RNE
    return (unsigned short)r;
}

__global__ void add_kernel(const float* __restrict__ a, const float* __restrict__ b,
                           float* __restrict__ o, int n) {
    int idx = (blockIdx.x * blockDim.x + threadIdx.x) * 4;
    if (idx < n) {
        float4 av = *(const float4*)(a + idx);
        float4 bv = *(const float4*)(b + idx);
        *(float4*)(o + idx) = make_float4(av.x + bv.x, av.y + bv.y, av.z + bv.z, av.w + bv.w);
    }
}

__global__ void cvt_bf16_kernel(const float* __restrict__ src, unsigned short* __restrict__ dst, int n) {
    int idx = (blockIdx.x * blockDim.x + threadIdx.x) * 4;
    if (idx < n) {
        float4 v = *(const float4*)(src + idx);
        ushort4 o;
        o.x = f2bf(v.x); o.y = f2bf(v.y); o.z = f2bf(v.z); o.w = f2bf(v.w);
        *(ushort4*)(dst + idx) = o;
    }
}

// ---------------- fp32 vector GEMM (round-1, unchanged) ----------------
constexpr int BM = 64, BN = 64, BK = 16;

template<int EPI, int WT>
__global__ __launch_bounds__(256)
void gemm_k(const float* __restrict__ X, const float* __restrict__ W,
            float* __restrict__ out,
            const float* __restrict__ e0, const float* __restrict__ e1,
            float* __restrict__ e2, const float* __restrict__ bvec,
            int M, int N, int K) {
    __shared__ float Xs[BK][BM + 4];
    __shared__ float Ws[BK][BN + 4];

    const int tid = threadIdx.x;
    const int bm = blockIdx.x * BM;
    const int bn = blockIdx.y * BN;

    const int lr = tid >> 2;
    const int lk = (tid & 3) << 2;
    const int wkr = tid >> 4;
    const int wnc = (tid & 15) << 2;

    const int tm = (tid & 15) << 2;
    const int tn = (tid >> 4) << 2;

    float acc[4][4] = {};

    for (int k0 = 0; k0 < K; k0 += BK) {
        float4 xv = *(const float4*)(X + (size_t)(bm + lr) * K + (k0 + lk));
        Xs[lk + 0][lr] = xv.x; Xs[lk + 1][lr] = xv.y;
        Xs[lk + 2][lr] = xv.z; Xs[lk + 3][lr] = xv.w;
        if (WT) {
            float4 wv = *(const float4*)(W + (size_t)(bn + lr) * K + (k0 + lk));
            Ws[lk + 0][lr] = wv.x; Ws[lk + 1][lr] = wv.y;
            Ws[lk + 2][lr] = wv.z; Ws[lk + 3][lr] = wv.w;
        } else {
            float4 wv = *(const float4*)(W + (size_t)(k0 + wkr) * N + (bn + wnc));
            *(float4*)&Ws[wkr][wnc] = wv;
        }
        __syncthreads();
#pragma unroll
        for (int k = 0; k < BK; ++k) {
            float4 a4 = *(const float4*)&Xs[k][tm];
            float4 b4 = *(const float4*)&Ws[k][tn];
            acc[0][0] = fmaf(a4.x, b4.x, acc[0][0]);
            acc[0][1] = fmaf(a4.x, b4.y, acc[0][1]);
            acc[0][2] = fmaf(a4.x, b4.z, acc[0][2]);
            acc[0][3] = fmaf(a4.x, b4.w, acc[0][3]);
            acc[1][0] = fmaf(a4.y, b4.x, acc[1][0]);
            acc[1][1] = fmaf(a4.y, b4.y, acc[1][1]);
            acc[1][2] = fmaf(a4.y, b4.z, acc[1][2]);
            acc[1][3] = fmaf(a4.y, b4.w, acc[1][3]);
            acc[2][0] = fmaf(a4.z, b4.x, acc[2][0]);
            acc[2][1] = fmaf(a4.z, b4.y, acc[2][1]);
            acc[2][2] = fmaf(a4.z, b4.z, acc[2][2]);
            acc[2][3] = fmaf(a4.z, b4.w, acc[2][3]);
            acc[3][0] = fmaf(a4.w, b4.x, acc[3][0]);
            acc[3][1] = fmaf(a4.w, b4.y, acc[3][1]);
            acc[3][2] = fmaf(a4.w, b4.z, acc[3][2]);
            acc[3][3] = fmaf(a4.w, b4.w, acc[3][3]);
        }
        __syncthreads();
    }

#pragma unroll
    for (int ii = 0; ii < 4; ++ii) {
        int row = bm + tm + ii;
#pragma unroll
        for (int jj = 0; jj < 4; ++jj) {
            int col = bn + tn + jj;
            size_t idx = (size_t)row * N + col;
            float v = acc[ii][jj];
            if (EPI == 0) {
                out[idx] = v;
            } else if (EPI == 1) {
                out[idx] = v - bvec[col];
            } else if (EPI == 2) {
                out[idx] = fmaxf(fmaf(-STEPV, v - e1[idx], e0[idx]), 0.0f);
            } else if (EPI == 3) {
                out[idx] = fmaxf(fmaf(-STEPV, v - e1[idx], e0[idx]), 0.0f) * e2[idx];
            } else if (EPI == 4) {
                out[idx] = e0[idx] - v;
            } else if (EPI == 5) {
                float act = (e0[idx] >= bvec[col] - TOLV) ? 1.0f : 0.0f;
                out[idx] = v * act;
                e2[idx] = act;
            }
        }
    }
}

// ---------------- bf16 MFMA iteration GEMM ----------------
// C = X @ W^T where X=[M,K] bf16 (lam), W=[N,K] bf16 (Q, symmetric).
// Tile 128(M) x 64(N), BK=64, 256 threads = 4 waves, wave tile 64x32.
// Epilogue: lamF_out = relu(lamF_in - STEP*(acc - e1)) [* act], also bf16 copy.
template<int EPI>  // 2: no mask, 3: * act
__global__ __launch_bounds__(256)
void mfma_it(const unsigned short* __restrict__ X, const unsigned short* __restrict__ W,
             const float* __restrict__ e0, const float* __restrict__ e1,
             const float* __restrict__ act,
             float* __restrict__ outF, unsigned short* __restrict__ outH,
             int M, int N, int K) {
    __shared__ short As[128 * 64];   // [row][k] packed, no pad (global_load_lds order)
    __shared__ short Bs[64 * 64];

    const int tid = threadIdx.x;
    const int w = tid >> 6;
    const int lane = tid & 63;
    const int bm = blockIdx.x * 128;
    const int bn = blockIdx.y * 64;
    const int wm = (w & 1) * 64;     // wave row offset in tile
    const int wn = (w >> 1) * 32;    // wave col offset in tile
    const int quad = lane >> 4;
    const int l15 = lane & 15;

    const int ldr = lane >> 3;        // 0..7
    const int ldc = (lane & 7) * 8;   // element col for 16B staging

    floatx4 acc[4][2] = {};

    for (int k0 = 0; k0 < K; k0 += 64) {
        // stage A: 128 rows x 64 cols bf16. wave w, issue t covers 8 rows.
#pragma unroll
        for (int t = 0; t < 4; ++t) {
            int row = t * 32 + w * 8 + ldr;
            const unsigned short* ga = X + (size_t)(bm + row) * K + k0 + ldc;
            short* la = As + (t * 32 + w * 8) * 64;   // wave-uniform base
            __builtin_amdgcn_global_load_lds(
                (const __attribute__((address_space(1))) void*)ga,
                (__attribute__((address_space(3))) void*)la, 16, 0, 0);
        }
        // stage B: 64 rows x 64 cols
#pragma unroll
        for (int t = 0; t < 2; ++t) {
            int row = t * 32 + w * 8 + ldr;
            const unsigned short* gb = W + (size_t)(bn + row) * K + k0 + ldc;
            short* lb = Bs + (t * 32 + w * 8) * 64;
            __builtin_amdgcn_global_load_lds(
                (const __attribute__((address_space(1))) void*)gb,
                (__attribute__((address_space(3))) void*)lb, 16, 0, 0);
        }
        __syncthreads();
#pragma unroll
        for (int kk = 0; kk < 2; ++kk) {
            const int ko = kk * 32 + quad * 8;
            short8 af[4], bf[2];
#pragma unroll
            for (int i = 0; i < 4; ++i)
                af[i] = *(const short8*)(As + (wm + i * 16 + l15) * 64 + ko);
#pragma unroll
            for (int i = 0; i < 2; ++i)
                bf[i] = *(const short8*)(Bs + (wn + i * 16 + l15) * 64 + ko);
#pragma unroll
            for (int mt = 0; mt < 4; ++mt)
#pragma unroll
                for (int nt = 0; nt < 2; ++nt)
                    acc[mt][nt] = __builtin_amdgcn_mfma_f32_16x16x32_bf16(
                        af[mt], bf[nt], acc[mt][nt], 0, 0, 0);
        }
        __syncthreads();
    }

    // epilogue: D[row = quad*4+r][col = lane&15] per 16x16 tile
#pragma unroll
    for (int mt = 0; mt < 4; ++mt) {
#pragma unroll
        for (int nt = 0; nt < 2; ++nt) {
#pragma unroll
            for (int r = 0; r < 4; ++r) {
                int row = bm + wm + mt * 16 + quad * 4 + r;
                int col = bn + wn + nt * 16 + l15;
                size_t idx = (size_t)row * N + col;
                float v = acc[mt][nt][r];
                float nv = fmaxf(fmaf(-STEPV, v - e1[idx], e0[idx]), 0.0f);
                if (EPI == 3) nv *= act[idx];
                outF[idx] = nv;
                outH[idx] = f2bf(nv);
            }
        }
    }
}

extern "C" void kernel_launch(void* const* d_in, const int* in_sizes, int n_in,
                              void* d_out, int out_size, void* d_ws, size_t ws_size,
                              hipStream_t stream) {
    const float* x = (const float*)d_in[0];  // [B,n]
    const float* u = (const float*)d_in[1];  // [B,n]
    const float* A = (const float*)d_in[2];  // [m,n]
    const float* b = (const float*)d_in[3];  // [m]
    float* out = (float*)d_out;              // [B,n]

    const int B = 4096, n = 512, m = 1024;
    const size_t Bm = (size_t)B * m;         // 4M
    const size_t Bn = (size_t)B * n;         // 2M

    float* ws = (float*)d_ws;
    unsigned short* Qbf = (unsigned short*)ws;          // m*m bf16  (0.5M floats)
    float* y      = ws + 524288;                        // [B,n] y=x+u, later z
    float* cbuf   = y + Bn;                             // [B,m] c, later masked
    float* lamF_A = cbuf + Bm;                          // [B,m] f32
    float* lamF_B = lamF_A + Bm;                        // [B,m] f32
    unsigned short* lamH_A = (unsigned short*)(lamF_B + Bm);  // [B,m] bf16
    unsigned short* lamH_B = lamH_A + Bm;                     // [B,m] bf16
    float* act    = (float*)(lamH_B + Bm);              // [B,m] f32 (Ax, then active)
    float* Qf     = act;                                // m*m f32 temp (dead before act is written)

    dim3 blk(256);

    // y = x + u
    add_kernel<<<(int)(Bn / 4 + 255) / 256, 256, 0, stream>>>(x, u, y, (int)Bn);

    // Q = A @ A^T (fp32), then convert to bf16
    gemm_k<0, 1><<<dim3(m / BM, m / BN), blk, 0, stream>>>(
        A, A, Qf, nullptr, nullptr, nullptr, nullptr, m, m, n);
    cvt_bf16_kernel<<<(m * m / 4 + 255) / 256, 256, 0, stream>>>(Qf, Qbf, m * m);

    // c = y @ A^T - b
    gemm_k<1, 1><<<dim3(B / BM, m / BN), blk, 0, stream>>>(
        y, A, cbuf, nullptr, nullptr, nullptr, b, B, m, n);

    // phase 1: lam=0; 50x lam = relu(lam - step*(lam@Q - c))
    hipMemsetAsync(lamF_A, 0, Bm * sizeof(float), stream);
    hipMemsetAsync(lamH_A, 0, Bm * sizeof(unsigned short), stream);
    float* lfin = lamF_A;  float* lfout = lamF_B;
    unsigned short* lhin = lamH_A;  unsigned short* lhout = lamH_B;
    for (int it = 0; it < PROJ_ITERS; ++it) {
        mfma_it<2><<<dim3(B / 128, m / 64), blk, 0, stream>>>(
            lhin, Qbf, lfin, cbuf, nullptr, lfout, lhout, B, m, m);
        float* tf = lfin; lfin = lfout; lfout = tf;
        unsigned short* th = lhin; lhin = lhout; lhout = th;
    }

    // z = y - lam @ A  (in-place into y)
    gemm_k<4, 0><<<dim3(B / BM, n / BN), blk, 0, stream>>>(
        lfin, A, y, y, nullptr, nullptr, nullptr, B, n, m);

    // Ax = z @ A^T -> act buffer
    gemm_k<0, 1><<<dim3(B / BM, m / BN), blk, 0, stream>>>(
        y, A, act, nullptr, nullptr, nullptr, nullptr, B, m, n);

    // masked = (u @ A^T) * active -> cbuf; active -> act (in place over Ax)
    gemm_k<5, 1><<<dim3(B / BM, m / BN), blk, 0, stream>>>(
        u, A, cbuf, act, nullptr, act, b, B, m, n);

    // phase 2: lam=0; 10x lam = relu(lam - step*(lam@Q - masked)) * active
    hipMemsetAsync(lamF_A, 0, Bm * sizeof(float), stream);
    hipMemsetAsync(lamH_A, 0, Bm * sizeof(unsigned short), stream);
    lfin = lamF_A; lfout = lamF_B; lhin = lamH_A; lhout = lamH_B;
    for (int it = 0; it < PROJU_ITERS; ++it) {
        mfma_it<3><<<dim3(B / 128, m / 64), blk, 0, stream>>>(
            lhin, Qbf, lfin, cbuf, act, lfout, lhout, B, m, m);
        float* tf = lfin; lfin = lfout; lfout = tf;
        unsigned short* th = lhin; lhin = lhout; lhout = th;
    }

    // out = u - lam @ A
    gemm_k<4, 0><<<dim3(B / BM, n / BN), blk, 0, stream>>>(
        lfin, A, out, u, nullptr, nullptr, nullptr, B, n, m);
}

// Round 3
// 1579.624 us; speedup vs baseline: 4.8205x; 1.2707x over previous
//
#include <hip/hip_runtime.h>

// ConvexPolytopeManifold: dual-PGD QP projection. B=4096, n=512, m=1024.
// Round 3:
//  - XOR-swizzled LDS staging (kills 16-way bank conflicts on frag ds_read_b128)
//  - z / Ax fp32 GEMMs eliminated algebraically: Ax - b = c - lam@Q
//  - ALL GEMMs on the bf16 MFMA path (Q, c, masked, out); fp32 lam master kept
//
// reference math:
//   Q = A@A^T; y = x+u; c = y@A^T - b
//   lam=0; 50x lam = relu(lam - 0.01*(lam@Q - c))
//   active = (c - lam@Q >= -TOL)                 [== Ax >= b - TOL]
//   masked = (u@A^T) * active
//   lam=0; 10x lam = relu(lam - 0.01*(lam@Q - masked)) * active
//   out = u - lam@A

#define PROJ_ITERS 50
#define PROJU_ITERS 10
#define TOLV 1e-5f
#define STEPV 0.01f

typedef __attribute__((ext_vector_type(8))) short short8;
typedef __attribute__((ext_vector_type(4))) float floatx4;
typedef unsigned short ushort_t;

__device__ inline ushort_t f2bf(float f) {
    union { float f; unsigned int u; } c; c.f = f;
    unsigned int u = c.u;
    return (ushort_t)((u + 0x7FFFu + ((u >> 16) & 1u)) >> 16);   // RNE
}
__device__ inline float bf2f(ushort_t h) {
    union { unsigned int u; float f; } c; c.u = ((unsigned int)h) << 16;
    return c.f;
}

// y_bf = bf16(x+u); u_bf = bf16(u)
__global__ void addcast_kernel(const float* __restrict__ x, const float* __restrict__ u,
                               ushort_t* __restrict__ ybf, ushort_t* __restrict__ ubf, int n) {
    int idx = (blockIdx.x * blockDim.x + threadIdx.x) * 4;
    if (idx < n) {
        float4 xv = *(const float4*)(x + idx);
        float4 uv = *(const float4*)(u + idx);
        ushort4 yo, uo;
        yo.x = f2bf(xv.x + uv.x); yo.y = f2bf(xv.y + uv.y);
        yo.z = f2bf(xv.z + uv.z); yo.w = f2bf(xv.w + uv.w);
        uo.x = f2bf(uv.x); uo.y = f2bf(uv.y); uo.z = f2bf(uv.z); uo.w = f2bf(uv.w);
        *(ushort4*)(ybf + idx) = yo;
        *(ushort4*)(ubf + idx) = uo;
    }
}

__global__ void cvt_bf16_kernel(const float* __restrict__ src, ushort_t* __restrict__ dst, int n) {
    int idx = (blockIdx.x * blockDim.x + threadIdx.x) * 4;
    if (idx < n) {
        float4 v = *(const float4*)(src + idx);
        ushort4 o;
        o.x = f2bf(v.x); o.y = f2bf(v.y); o.z = f2bf(v.z); o.w = f2bf(v.w);
        *(ushort4*)(dst + idx) = o;
    }
}

// AT[j,i] = bf16(A[i,j]);  A is [m,n] row-major.  32x32 LDS tile.
__global__ void transpose_cast_kernel(const float* __restrict__ A, ushort_t* __restrict__ AT,
                                      int m, int n) {
    __shared__ float t[32][33];
    int bx = blockIdx.x * 32;   // col range (n)
    int by = blockIdx.y * 32;   // row range (m)
    int tx = threadIdx.x & 31, ty = threadIdx.x >> 5;   // 32 x 8
#pragma unroll
    for (int i = 0; i < 32; i += 8)
        t[ty + i][tx] = A[(size_t)(by + ty + i) * n + bx + tx];
    __syncthreads();
#pragma unroll
    for (int i = 0; i < 32; i += 8)
        AT[(size_t)(bx + ty + i) * m + by + tx] = f2bf(t[tx][ty + i]);
}

// ---------------- generic bf16 MFMA GEMM:  C = X @ W^T ----------------
// X=[M,K] bf16, W=[N,K] bf16. Tile 128(M)x64(N), BK=64, 256 thr = 4 waves,
// wave tile 64x32 (4x2 of 16x16x32). XOR-swizzled LDS (chunk = 8 bf16 = 16B):
// physical slot s of row r holds global chunk s ^ (r&7)  -> frag reads <=2-way.
// EPI: 0 Q(outH=bf16(acc)); 1 c(outF=acc-bvec[col]); 2 iter; 3 iter*act;
//      4 act(outH=(e1-acc>=-TOL)); 5 outF=acc*act; 6 outF=e0-acc
template<int EPI>
__global__ __launch_bounds__(256)
void mfma_g(const ushort_t* __restrict__ X, const ushort_t* __restrict__ W,
            const float* __restrict__ e0, const float* __restrict__ e1,
            const ushort_t* __restrict__ actb,
            float* __restrict__ outF, ushort_t* __restrict__ outH,
            const float* __restrict__ bvec,
            int M, int N, int K) {
    __shared__ short As[128 * 64];
    __shared__ short Bs[64 * 64];

    const int tid = threadIdx.x;
    const int w = tid >> 6;
    const int lane = tid & 63;
    const int bm = blockIdx.x * 128;
    const int bn = blockIdx.y * 64;
    const int wm = (w & 1) * 64;
    const int wn = (w >> 1) * 32;
    const int quad = lane >> 4;
    const int l15 = lane & 15;

    const int ldr = lane >> 3;                       // 0..7 row in 8-row group
    const int csw = ((lane & 7) ^ ldr) * 8;          // swizzled source chunk (elements)

    floatx4 acc[4][2] = {};

    for (int k0 = 0; k0 < K; k0 += 64) {
#pragma unroll
        for (int t = 0; t < 4; ++t) {
            int row = t * 32 + w * 8 + ldr;
            const ushort_t* ga = X + (size_t)(bm + row) * K + k0 + csw;
            short* la = As + (t * 32 + w * 8) * 64;          // wave-uniform base
            __builtin_amdgcn_global_load_lds(
                (const __attribute__((address_space(1))) void*)ga,
                (__attribute__((address_space(3))) void*)la, 16, 0, 0);
        }
#pragma unroll
        for (int t = 0; t < 2; ++t) {
            int row = t * 32 + w * 8 + ldr;
            const ushort_t* gb = W + (size_t)(bn + row) * K + k0 + csw;
            short* lb = Bs + (t * 32 + w * 8) * 64;
            __builtin_amdgcn_global_load_lds(
                (const __attribute__((address_space(1))) void*)gb,
                (__attribute__((address_space(3))) void*)lb, 16, 0, 0);
        }
        __syncthreads();
#pragma unroll
        for (int kk = 0; kk < 2; ++kk) {
            const int sw = ((kk * 4 + quad) ^ (l15 & 7)) * 8;   // de-swizzle
            short8 af[4], bfr[2];
#pragma unroll
            for (int i = 0; i < 4; ++i)
                af[i] = *(const short8*)(As + (wm + i * 16 + l15) * 64 + sw);
#pragma unroll
            for (int i = 0; i < 2; ++i)
                bfr[i] = *(const short8*)(Bs + (wn + i * 16 + l15) * 64 + sw);
#pragma unroll
            for (int mt = 0; mt < 4; ++mt)
#pragma unroll
                for (int nt = 0; nt < 2; ++nt)
                    acc[mt][nt] = __builtin_amdgcn_mfma_f32_16x16x32_bf16(
                        af[mt], bfr[nt], acc[mt][nt], 0, 0, 0);
        }
        __syncthreads();
    }

    // C/D layout: row = quad*4 + r, col = lane&15 within each 16x16 tile
#pragma unroll
    for (int mt = 0; mt < 4; ++mt) {
#pragma unroll
        for (int nt = 0; nt < 2; ++nt) {
#pragma unroll
            for (int r = 0; r < 4; ++r) {
                int row = bm + wm + mt * 16 + quad * 4 + r;
                int col = bn + wn + nt * 16 + l15;
                size_t idx = (size_t)row * N + col;
                float v = acc[mt][nt][r];
                if (EPI == 0) {
                    outH[idx] = f2bf(v);
                } else if (EPI == 1) {
                    outF[idx] = v - bvec[col];
                } else if (EPI == 2) {
                    float nv = fmaxf(fmaf(-STEPV, v - e1[idx], e0[idx]), 0.0f);
                    outF[idx] = nv;
                    outH[idx] = f2bf(nv);
                } else if (EPI == 3) {
                    float nv = fmaxf(fmaf(-STEPV, v - e1[idx], e0[idx]), 0.0f) * bf2f(actb[idx]);
                    outF[idx] = nv;
                    outH[idx] = f2bf(nv);
                } else if (EPI == 4) {
                    outH[idx] = (e1[idx] - v >= -TOLV) ? (ushort_t)0x3F80 : (ushort_t)0;
                } else if (EPI == 5) {
                    outF[idx] = v * bf2f(actb[idx]);
                } else if (EPI == 6) {
                    outF[idx] = e0[idx] - v;
                }
            }
        }
    }
}

extern "C" void kernel_launch(void* const* d_in, const int* in_sizes, int n_in,
                              void* d_out, int out_size, void* d_ws, size_t ws_size,
                              hipStream_t stream) {
    const float* x = (const float*)d_in[0];  // [B,n]
    const float* u = (const float*)d_in[1];  // [B,n]
    const float* A = (const float*)d_in[2];  // [m,n]
    const float* b = (const float*)d_in[3];  // [m]
    float* out = (float*)d_out;              // [B,n]

    const int B = 4096, n = 512, m = 1024;
    const size_t Bm = (size_t)B * m;         // 4M
    const size_t Bn = (size_t)B * n;         // 2M

    // ---- workspace layout (~84 MB) ----
    ushort_t* A_bf   = (ushort_t*)d_ws;            // [m,n]  0.5M
    ushort_t* AT_bf  = A_bf + (size_t)m * n;       // [n,m]  0.5M
    ushort_t* y_bf   = AT_bf + (size_t)n * m;      // [B,n]  2M
    ushort_t* u_bf   = y_bf + Bn;                  // [B,n]  2M
    ushort_t* Qbf    = u_bf + Bn;                  // [m,m]  1M
    ushort_t* lamH_A = Qbf + (size_t)m * m;        // [B,m]  4M
    ushort_t* lamH_B = lamH_A + Bm;                // [B,m]  4M
    ushort_t* act    = lamH_B + Bm;                // [B,m]  4M (bf16 0/1)
    float* cbuf   = (float*)(act + Bm);            // [B,m] f32 (c, then masked)
    float* lamF_A = cbuf + Bm;                     // [B,m] f32
    float* lamF_B = lamF_A + Bm;                   // [B,m] f32

    dim3 blk(256);

    // casts
    addcast_kernel<<<(int)(Bn / 4 + 255) / 256, 256, 0, stream>>>(x, u, y_bf, u_bf, (int)Bn);
    cvt_bf16_kernel<<<(m * n / 4 + 255) / 256, 256, 0, stream>>>(A, A_bf, m * n);
    transpose_cast_kernel<<<dim3(n / 32, m / 32), blk, 0, stream>>>(A, AT_bf, m, n);

    // Q = bf16(A @ A^T)
    mfma_g<0><<<dim3(m / 128, m / 64), blk, 0, stream>>>(
        A_bf, A_bf, nullptr, nullptr, nullptr, nullptr, Qbf, nullptr, m, m, n);

    // c = y @ A^T - b
    mfma_g<1><<<dim3(B / 128, m / 64), blk, 0, stream>>>(
        y_bf, A_bf, nullptr, nullptr, nullptr, cbuf, nullptr, b, B, m, n);

    // phase 1: 50x lam = relu(lam - step*(lam@Q - c))
    hipMemsetAsync(lamF_A, 0, Bm * sizeof(float), stream);
    hipMemsetAsync(lamH_A, 0, Bm * sizeof(ushort_t), stream);
    float* lfin = lamF_A; float* lfout = lamF_B;
    ushort_t* lhin = lamH_A; ushort_t* lhout = lamH_B;
    for (int it = 0; it < PROJ_ITERS; ++it) {
        mfma_g<2><<<dim3(B / 128, m / 64), blk, 0, stream>>>(
            lhin, Qbf, lfin, cbuf, nullptr, lfout, lhout, nullptr, B, m, m);
        float* tf = lfin; lfin = lfout; lfout = tf;
        ushort_t* th = lhin; lhin = lhout; lhout = th;
    }

    // active = (c - lam@Q >= -TOL)   [bf16 0/1]
    mfma_g<4><<<dim3(B / 128, m / 64), blk, 0, stream>>>(
        lhin, Qbf, nullptr, cbuf, nullptr, nullptr, act, nullptr, B, m, m);

    // masked = (u @ A^T) * active -> cbuf (overwrite)
    mfma_g<5><<<dim3(B / 128, m / 64), blk, 0, stream>>>(
        u_bf, A_bf, nullptr, nullptr, act, cbuf, nullptr, nullptr, B, m, n);

    // phase 2: 10x lam = relu(lam - step*(lam@Q - masked)) * active
    hipMemsetAsync(lamF_A, 0, Bm * sizeof(float), stream);
    hipMemsetAsync(lamH_A, 0, Bm * sizeof(ushort_t), stream);
    lfin = lamF_A; lfout = lamF_B; lhin = lamH_A; lhout = lamH_B;
    for (int it = 0; it < PROJU_ITERS; ++it) {
        mfma_g<3><<<dim3(B / 128, m / 64), blk, 0, stream>>>(
            lhin, Qbf, lfin, cbuf, act, lfout, lhout, nullptr, B, m, m);
        float* tf = lfin; lfin = lfout; lfout = tf;
        ushort_t* th = lhin; lhin = lhout; lhout = th;
    }

    // out = u - lam @ A   (B-operand = A^T as [n,m] bf16)
    mfma_g<6><<<dim3(B / 128, n / 64), blk, 0, stream>>>(
        lhin, AT_bf, u, nullptr, nullptr, out, nullptr, nullptr, B, n, m);
}